// Round 24
// baseline (254.193 us; speedup 1.0000x reference)
//
#include <hip/hip_runtime.h>
#include <math.h>

#define B_  4
#define T_  2048
#define DM  1024
#define H_  16
#define DK  64
#define N3  3072

typedef __attribute__((ext_vector_type(8))) __bf16 bf16x8;
typedef __attribute__((ext_vector_type(4))) float f32x4;
typedef __attribute__((ext_vector_type(4))) unsigned int u32x4;

static __device__ __forceinline__ unsigned int f2bf(float f) {
    union { float f; unsigned int u; } v; v.f = f;
    return (v.u + 0x7fffu + ((v.u >> 16) & 1u)) >> 16;   // RNE
}
static __device__ __forceinline__ unsigned int pack2bf(float a, float b) {
    return f2bf(a) | (f2bf(b) << 16);
}
// async global->LDS, 16B per lane; LDS dest = first-lane base + lane*16 (linear)
static __device__ __forceinline__ void gload_lds16(const void* g, void* l) {
    __builtin_amdgcn_global_load_lds(
        (const __attribute__((address_space(1))) unsigned int*)g,
        (__attribute__((address_space(3))) unsigned int*)l, 16, 0, 0);
}

// ---------------- prep: x fp32->bf16 copy (blocks 0..4095) + RoPE table (4096..4351) ----
__global__ __launch_bounds__(256)
void prep_x_rope(const float* __restrict__ src, unsigned short* __restrict__ dst,
                 const int* __restrict__ pos, float2* __restrict__ RC)
{
    const int blk = blockIdx.x;
    if (blk < 4096) {
        const int i = blk * 256 + threadIdx.x;     // 1048576 u32x4 chunks
        const float4 f0 = ((const float4*)src)[i * 2];
        const float4 f1 = ((const float4*)src)[i * 2 + 1];
        u32x4 wv;
        wv.x = pack2bf(f0.x, f0.y); wv.y = pack2bf(f0.z, f0.w);
        wv.z = pack2bf(f1.x, f1.y); wv.w = pack2bf(f1.z, f1.w);
        ((u32x4*)dst)[i] = wv;
    } else {
        const int i = (blk - 4096) * 256 + threadIdx.x;   // 65536 entries
        const int t = i >> 5, dp = i & 31;
        const float ifr = __powf(10000.0f, -(float)(2 * dp) * (1.0f / 64.0f));
        float s, c;
        __sincosf((float)pos[t] * ifr, &s, &c);
        RC[i] = make_float2(c, s);
    }
}

// ---------------- prep: fp32 [K][N] -> bf16 transposed [N][K] ----------------
__global__ __launch_bounds__(256)
void convert_T(const float* __restrict__ src, unsigned short* __restrict__ dst, int K, int N)
{
    __shared__ float tile[32][33];
    const int n0 = blockIdx.x * 32, k0 = blockIdx.y * 32;
    const int tid = threadIdx.x;
    #pragma unroll
    for (int p = 0; p < 4; ++p) {
        const int idx = p * 256 + tid;
        const int r = idx >> 5, c = idx & 31;
        tile[r][c] = src[(size_t)(k0 + r) * N + n0 + c];
    }
    __syncthreads();
    #pragma unroll
    for (int p = 0; p < 4; ++p) {
        const int idx = p * 256 + tid;
        const int r = idx >> 5, c = idx & 31;
        dst[(size_t)(n0 + r) * K + k0 + c] = (unsigned short)f2bf(tile[c][r]);
    }
}

// ============ Kernel 1: QKV GEMM (bf16 MFMA) + RoPE, 3-buffer counted-vmcnt pipeline ====
__global__ __launch_bounds__(256, 3)
void qkv_rope_kernel(const unsigned short* __restrict__ xb,     // [8192][1024] bf16
                     const unsigned short* __restrict__ WT,     // [3072][1024] bf16 (Wqkv^T)
                     const float2* __restrict__ RC,             // [2048][32] {cos,sin}
                     unsigned short* __restrict__ Qb,
                     unsigned short* __restrict__ Kb,
                     unsigned short* __restrict__ Vtb)
{
    __shared__ u32x4 Asv[3][512];   // [buf][kb 4][row 128]; 24 KB
    __shared__ u32x4 Bsv[3][512];   // 24 KB; total 48 KB -> 3 blocks/CU
    const int tid  = threadIdx.x;
    const int lin  = blockIdx.x;          // 1536 = 8 XCDs * 3 cols * 64 rows
    const int xcd  = lin & 7;
    const int idx  = lin >> 3;            // 0..191
    const int col0 = (xcd * 3 + (idx % 3)) * 128;
    const int row0 = (idx / 3) * 128;
    const int l = tid & 63, w = tid >> 6;
    const int wr = w >> 1, wc = w & 1;
    const int lr = l & 15, hi4 = l >> 4;

    const int srow = tid & 127;
    const int kel  = (tid >> 7) * 8;
    const size_t a0 = (size_t)(row0 + srow) * DM + kel;
    const size_t b0 = (size_t)(col0 + srow) * DM + kel;

    f32x4 acc[4][4];
    #pragma unroll
    for (int m = 0; m < 4; ++m)
        #pragma unroll
        for (int n = 0; n < 4; ++n)
            acc[m][n] = (f32x4){0.f, 0.f, 0.f, 0.f};

    // prologue: slab 0 -> buf0, slab 1 -> buf1 (8 loads outstanding)
    gload_lds16(&xb[a0],      &Asv[0][tid]);
    gload_lds16(&xb[a0 + 16], &Asv[0][256 + tid]);
    gload_lds16(&WT[b0],      &Bsv[0][tid]);
    gload_lds16(&WT[b0 + 16], &Bsv[0][256 + tid]);
    gload_lds16(&xb[a0 + 32], &Asv[1][tid]);
    gload_lds16(&xb[a0 + 48], &Asv[1][256 + tid]);
    gload_lds16(&WT[b0 + 32], &Bsv[1][tid]);
    gload_lds16(&WT[b0 + 48], &Bsv[1][256 + tid]);
    asm volatile("s_waitcnt vmcnt(4)" ::: "memory");   // slab 0 landed
    __builtin_amdgcn_s_barrier();

    #pragma unroll 1
    for (int it = 0; it < 32; ++it) {
        const int cur = it % 3;
        const bool more = (it + 2 < 32);
        if (more) {                        // prefetch slab it+2 into buf (it+2)%3
            const int nb = (it + 2) % 3;
            const int kn = (it + 2) * 32;
            gload_lds16(&xb[a0 + kn],      &Asv[nb][tid]);
            gload_lds16(&xb[a0 + kn + 16], &Asv[nb][256 + tid]);
            gload_lds16(&WT[b0 + kn],      &Bsv[nb][tid]);
            gload_lds16(&WT[b0 + kn + 16], &Bsv[nb][256 + tid]);
        }
        u32x4 a[4], b[4];
        #pragma unroll
        for (int m = 0; m < 4; ++m) a[m] = Asv[cur][hi4 * 128 + wr * 64 + m * 16 + lr];
        #pragma unroll
        for (int n = 0; n < 4; ++n) b[n] = Bsv[cur][hi4 * 128 + wc * 64 + n * 16 + lr];
        #pragma unroll
        for (int m = 0; m < 4; ++m)
            #pragma unroll
            for (int n = 0; n < 4; ++n)
                acc[m][n] = __builtin_amdgcn_mfma_f32_16x16x32_bf16(
                    __builtin_bit_cast(bf16x8, a[m]),
                    __builtin_bit_cast(bf16x8, b[n]),
                    acc[m][n], 0, 0, 0);
        if (more) asm volatile("s_waitcnt vmcnt(4)" ::: "memory");
        else      asm volatile("s_waitcnt vmcnt(0)" ::: "memory");
        __builtin_amdgcn_s_barrier();
    }

    const int which = col0 >> 10;                      // 0=q 1=k 2=v (tile never crosses)
    const int h     = ((col0 & 1023) >> 6) + wc;
    const int bb    = row0 >> 11;
    const int t0w   = (row0 & 2047) + wr * 64;

    if (which == 2) {
        // V: lane holds t-run of 4 for fixed d -> free transpose, write Vt[d][t]
        #pragma unroll
        for (int n = 0; n < 4; ++n) {
            const int d = n * 16 + lr;
            #pragma unroll
            for (int m = 0; m < 4; ++m) {
                uint2 val;
                val.x = pack2bf(acc[m][n][0], acc[m][n][1]);
                val.y = pack2bf(acc[m][n][2], acc[m][n][3]);
                *(uint2*)&Vtb[((size_t)(bb * H_ + h) * DK + d) * T_ + t0w + m * 16 + hi4 * 4] = val;
            }
        }
    } else {
        unsigned short* dst = (which == 0) ? Qb : Kb;
        const float postscale = (which == 0) ? 0.125f : 1.0f;   // fold 1/sqrt(dk) into Q
        #pragma unroll
        for (int n = 0; n < 4; ++n) {
            const int d  = n * 16 + lr;
            const int dp = d >> 1;
            #pragma unroll
            for (int m = 0; m < 4; ++m)
                #pragma unroll
                for (int r = 0; r < 4; ++r) {
                    const int t = t0w + m * 16 + hi4 * 4 + r;
                    const float v = acc[m][n][r];
                    const float partner = __shfl_xor(v, 1, 64);   // pair (d^1)
                    const float2 cs = RC[t * 32 + dp];            // {cos, sin}
                    const float rv = ((d & 1) ? (partner * cs.y + v * cs.x)
                                              : (v * cs.x - partner * cs.y)) * postscale;
                    dst[((size_t)(bb * H_ + h) * T_ + t) * DK + d] = (unsigned short)f2bf(rv);
                }
        }
    }
}

// ============ Kernel 2: causal flash attention, Q-tile 256 (8 waves), T14 staging ============
// XCD swizzle: lin%8 = headgroup%8 -> all 8 q-blocks of one head on one XCD.
// T5: s_setprio(1) around MFMA clusters (scheduler hint only; zero correctness risk).
__global__ __launch_bounds__(512)
void flash_attn_kernel(const unsigned short* __restrict__ Qg,
                       const unsigned short* __restrict__ Kg,
                       const unsigned short* __restrict__ Vtg,
                       unsigned short* __restrict__ Og)
{
    __shared__ u32x4 K4[512];              // [kv 64][chunk 8], chunk ^= kv&7
    __shared__ u32x4 Vt4[512];             // [d 64][chunk 8],  chunk ^= d&7
    __shared__ unsigned int Pex[8][16 * 36];  // per-wave [q 16][word], stride 36

    const int tid = threadIdx.x;
    const int l = tid & 63, w = tid >> 6;  // w in 0..7
    const int lr = l & 15, hi4 = l >> 4;
    const int lin = blockIdx.x;            // 512 blocks
    const int qt  = 7 - (lin >> 6);        // longest q-tiles first
    const int g   = lin & 63;              // headgroup: same g -> same XCD (g%8)
    const int h   = g & 15, b = g >> 4;
    const int q0 = qt * 256;
    const size_t hb = (size_t)(b * H_ + h) * T_ * DK;
    unsigned int* pw = &Pex[w][0];

    // staging coords: thread owns exactly 1 chunk of K and 1 of Vt
    const int srow = tid >> 3, scc = tid & 7;
    const int sdst = srow * 8 + (scc ^ (srow & 7));

    // Q fragments (B-operand: col=lr -> q-row, k=d=ks*32+hi4*8+j)
    u32x4 qf[2][2];
    #pragma unroll
    for (int m = 0; m < 2; ++m)
        #pragma unroll
        for (int ks = 0; ks < 2; ++ks)
            qf[m][ks] = *(const u32x4*)&Qg[hb + (size_t)(q0 + w * 32 + m * 16 + lr) * DK
                                           + ks * 32 + hi4 * 8];

    f32x4 acc_ot[2][4];                    // [m][df]: O^T frag, col=q(lr), row=d
    float m_i[2], l_i[2];
    #pragma unroll
    for (int m = 0; m < 2; ++m) {
        m_i[m] = -INFINITY; l_i[m] = 0.f;
        #pragma unroll
        for (int df = 0; df < 4; ++df) acc_ot[m][df] = (f32x4){0.f, 0.f, 0.f, 0.f};
    }

    const int qwave = q0 + w * 32;
    const int nkt = (q0 >> 6) + 4;         // K/V tiles covering q0..q0+255

    // prologue: issue loads for tile 0
    u32x4 kr = *(const u32x4*)&Kg [hb + (size_t)srow * DK + scc * 8];
    u32x4 vr = *(const u32x4*)&Vtg[hb + (size_t)srow * T_ + scc * 8];

    for (int kt = 0; kt < nkt; ++kt) {
        const int kv0 = kt * 64;
        __syncthreads();                   // prev iter's LDS reads done
        K4[sdst] = kr; Vt4[sdst] = vr;
        __syncthreads();                   // staged data visible
        if (kt + 1 < nkt) {                // issue NEXT tile's loads; latency hides under compute
            const int kvn = kv0 + 64;
            kr = *(const u32x4*)&Kg [hb + (size_t)(kvn + srow) * DK + scc * 8];
            vr = *(const u32x4*)&Vtg[hb + (size_t)srow * T_ + kvn + scc * 8];
        }
        if (kv0 > qwave + 31) continue;    // wave-uniform: fully masked

        // ---- S^T = mfma(K, Q): D col=q(lr), row=kv(nf*16+hi4*4+r) ----
        f32x4 st[2][4];
        #pragma unroll
        for (int m = 0; m < 2; ++m)
            #pragma unroll
            for (int nf = 0; nf < 4; ++nf)
                st[m][nf] = (f32x4){0.f, 0.f, 0.f, 0.f};
        __builtin_amdgcn_s_setprio(1);
        #pragma unroll
        for (int ks = 0; ks < 2; ++ks) {
            u32x4 kb4[4];
            #pragma unroll
            for (int nf = 0; nf < 4; ++nf) {
                const int row = nf * 16 + lr;
                kb4[nf] = K4[row * 8 + ((ks * 4 + hi4) ^ (row & 7))];
            }
            #pragma unroll
            for (int m = 0; m < 2; ++m)
                #pragma unroll
                for (int nf = 0; nf < 4; ++nf)
                    st[m][nf] = __builtin_amdgcn_mfma_f32_16x16x32_bf16(
                        __builtin_bit_cast(bf16x8, kb4[nf]),
                        __builtin_bit_cast(bf16x8, qf[m][ks]), st[m][nf], 0, 0, 0);
        }
        __builtin_amdgcn_s_setprio(0);

        const bool needmask = (kv0 + 63 > qwave);
        u32x4 pfrag[2][2];
        #pragma unroll
        for (int m = 0; m < 2; ++m) {
            const int qg = qwave + m * 16 + lr;
            float sv[4][4];
            #pragma unroll
            for (int nf = 0; nf < 4; ++nf)
                #pragma unroll
                for (int r = 0; r < 4; ++r) {
                    float xv = st[m][nf][r];
                    if (needmask && (kv0 + nf * 16 + hi4 * 4 + r) > qg) xv = -INFINITY;
                    sv[nf][r] = xv;
                }
            // row max: 15 local + 2 shuffles (over hi4 groups)
            float mx = sv[0][0];
            #pragma unroll
            for (int nf = 0; nf < 4; ++nf)
                #pragma unroll
                for (int r = 0; r < 4; ++r) mx = fmaxf(mx, sv[nf][r]);
            mx = fmaxf(mx, __shfl_xor(mx, 16, 64));
            mx = fmaxf(mx, __shfl_xor(mx, 32, 64));
            const float mnew = fmaxf(m_i[m], mx);
            const float alpha = __expf(m_i[m] - mnew);
            m_i[m] = mnew;
            float p[4][4], rs = 0.f;
            #pragma unroll
            for (int nf = 0; nf < 4; ++nf)
                #pragma unroll
                for (int r = 0; r < 4; ++r) {
                    p[nf][r] = __expf(sv[nf][r] - mnew);
                    rs += p[nf][r];
                }
            rs += __shfl_xor(rs, 16, 64);
            rs += __shfl_xor(rs, 32, 64);
            l_i[m] = l_i[m] * alpha + rs;
            #pragma unroll
            for (int df = 0; df < 4; ++df) acc_ot[m][df] *= alpha;
            // pack P row -> per-wave LDS exchange [q=lr][word=kv/2], stride 36
            #pragma unroll
            for (int nf = 0; nf < 4; ++nf) {
                uint2 pr;
                pr.x = pack2bf(p[nf][0], p[nf][1]);
                pr.y = pack2bf(p[nf][2], p[nf][3]);
                *(uint2*)&pw[lr * 36 + nf * 8 + hi4 * 2] = pr;
            }
            // read back as B-frag: col=q(lr), k = kv = ks*32 + hi4*8 + j
            #pragma unroll
            for (int ks = 0; ks < 2; ++ks)
                pfrag[m][ks] = *(const u32x4*)&pw[lr * 36 + ks * 16 + hi4 * 4];
        }

        // ---- O^T += mfma(Vt, P): col=q(lr), row=d ----
        __builtin_amdgcn_s_setprio(1);
        #pragma unroll
        for (int ks = 0; ks < 2; ++ks) {
            u32x4 vb[4];
            #pragma unroll
            for (int df = 0; df < 4; ++df) {
                const int d = df * 16 + lr;
                vb[df] = Vt4[d * 8 + ((ks * 4 + hi4) ^ (d & 7))];
            }
            #pragma unroll
            for (int m = 0; m < 2; ++m)
                #pragma unroll
                for (int df = 0; df < 4; ++df)
                    acc_ot[m][df] = __builtin_amdgcn_mfma_f32_16x16x32_bf16(
                        __builtin_bit_cast(bf16x8, vb[df]),
                        __builtin_bit_cast(bf16x8, pfrag[m][ks]), acc_ot[m][df], 0, 0, 0);
        }
        __builtin_amdgcn_s_setprio(0);
    }

    // ---- epilogue: O^T -> O via per-wave LDS, then coalesced bf16 stores ----
    #pragma unroll
    for (int m = 0; m < 2; ++m) {
        const float inv = 1.0f / l_i[m];
        #pragma unroll
        for (int df = 0; df < 4; ++df) {
            uint2 pr;
            pr.x = pack2bf(acc_ot[m][df][0] * inv, acc_ot[m][df][1] * inv);
            pr.y = pack2bf(acc_ot[m][df][2] * inv, acc_ot[m][df][3] * inv);
            *(uint2*)&pw[lr * 36 + df * 8 + hi4 * 2] = pr;
        }
        #pragma unroll
        for (int ks2 = 0; ks2 < 2; ++ks2) {
            const u32x4 ov = *(const u32x4*)&pw[lr * 36 + ks2 * 16 + hi4 * 4];
            *(u32x4*)&Og[hb + (size_t)(qwave + m * 16 + lr) * DK + ks2 * 32 + hi4 * 8] = ov;
        }
    }
}

// ============ Kernel 3: output projection (bf16 MFMA), XCD-ownership swizzle ============
__global__ __launch_bounds__(256)
void out_proj_kernel(const unsigned short* __restrict__ Ob,   // [b][h][t][d] bf16
                     const unsigned short* __restrict__ WoT,  // [1024][1024] bf16 (Wo^T)
                     float* __restrict__ out)
{
    __shared__ u32x4 Asv[512];
    __shared__ u32x4 Bsv[512];
    const int tid  = threadIdx.x;
    const int lin  = blockIdx.x;          // 512 = 8 XCDs * 64 rows
    const int col0 = (lin & 7) * 128;
    const int row0 = (lin >> 3) * 128;
    const int l = tid & 63, w = tid >> 6;
    const int wr = w >> 1, wc = w & 1;
    const int lr = l & 15, hi4 = l >> 4;
    const int bb = row0 >> 11, trow0 = row0 & 2047;

    f32x4 acc[4][4];
    #pragma unroll
    for (int m = 0; m < 4; ++m)
        #pragma unroll
        for (int n = 0; n < 4; ++n)
            acc[m][n] = (f32x4){0.f, 0.f, 0.f, 0.f};

    for (int k0 = 0; k0 < DM; k0 += 32) {
        __syncthreads();
        #pragma unroll
        for (int pass = 0; pass < 2; ++pass) {
            const int i = pass * 256 + tid;
            const int row = i & 127, kb = i >> 7;
            const int k = k0 + kb * 8;
            const int hh = k >> 6, dd = k & 63;
            gload_lds16(&Ob[((size_t)(bb * H_ + hh) * T_ + trow0 + row) * DK + dd], &Asv[i]);
            gload_lds16(&WoT[(size_t)(col0 + row) * DM + k0 + kb * 8], &Bsv[i]);
        }
        __syncthreads();
        u32x4 a[4], b[4];
        #pragma unroll
        for (int m = 0; m < 4; ++m) a[m] = Asv[hi4 * 128 + wr * 64 + m * 16 + lr];
        #pragma unroll
        for (int n = 0; n < 4; ++n) b[n] = Bsv[hi4 * 128 + wc * 64 + n * 16 + lr];
        #pragma unroll
        for (int m = 0; m < 4; ++m)
            #pragma unroll
            for (int n = 0; n < 4; ++n)
                acc[m][n] = __builtin_amdgcn_mfma_f32_16x16x32_bf16(
                    __builtin_bit_cast(bf16x8, a[m]),
                    __builtin_bit_cast(bf16x8, b[n]),
                    acc[m][n], 0, 0, 0);
    }

    #pragma unroll
    for (int n = 0; n < 4; ++n) {
        const int gc = col0 + wc * 64 + n * 16 + lr;
        #pragma unroll
        for (int m = 0; m < 4; ++m)
            #pragma unroll
            for (int r = 0; r < 4; ++r)
                out[(size_t)(row0 + wr * 64 + m * 16 + hi4 * 4 + r) * DM + gc] = acc[m][n][r];
    }
}

extern "C" void kernel_launch(void* const* d_in, const int* in_sizes, int n_in,
                              void* d_out, int out_size, void* d_ws, size_t ws_size,
                              hipStream_t stream)
{
    const float* x    = (const float*)d_in[0];
    const float* Wqkv = (const float*)d_in[1];
    const float* Wo   = (const float*)d_in[2];
    const int*   pos  = (const int*)d_in[3];
    float* out = (float*)d_out;

    unsigned short* ws    = (unsigned short*)d_ws;
    unsigned short* xb    = ws;                      // 8388608
    unsigned short* WqkvT = xb    + 8388608;         // 3145728
    unsigned short* WoT   = WqkvT + 3145728;         // 1048576
    unsigned short* Qb    = WoT   + 1048576;         // 8388608
    unsigned short* Kb    = Qb    + 8388608;         // 8388608
    unsigned short* Vtb   = Kb    + 8388608;         // 8388608  ([b][h][d][t])
    unsigned short* Ob    = Vtb   + 8388608;         // 8388608
    float2*         RC    = (float2*)(Ob + 8388608); // 65536 float2 = 512 KB

    prep_x_rope<<<dim3(4352), 256, 0, stream>>>(x, xb, pos, RC);
    convert_T<<<dim3(96, 32), 256, 0, stream>>>(Wqkv, WqkvT, 1024, 3072);
    convert_T<<<dim3(32, 32), 256, 0, stream>>>(Wo, WoT, 1024, 1024);
    qkv_rope_kernel<<<dim3(1536), 256, 0, stream>>>(xb, WqkvT, RC, Qb, Kb, Vtb);
    flash_attn_kernel<<<dim3(512), 512, 0, stream>>>(Qb, Kb, Vtb, Ob);
    out_proj_kernel<<<dim3(512), 256, 0, stream>>>(Ob, WoT, out);
}

// Round 25
// 252.389 us; speedup vs baseline: 1.0071x; 1.0071x over previous
//
#include <hip/hip_runtime.h>
#include <math.h>

#define B_  4
#define T_  2048
#define DM  1024
#define H_  16
#define DK  64
#define N3  3072

typedef __attribute__((ext_vector_type(8))) __bf16 bf16x8;
typedef __attribute__((ext_vector_type(4))) float f32x4;
typedef __attribute__((ext_vector_type(4))) unsigned int u32x4;

static __device__ __forceinline__ unsigned int f2bf(float f) {
    union { float f; unsigned int u; } v; v.f = f;
    return (v.u + 0x7fffu + ((v.u >> 16) & 1u)) >> 16;   // RNE
}
static __device__ __forceinline__ unsigned int pack2bf(float a, float b) {
    return f2bf(a) | (f2bf(b) << 16);
}
// async global->LDS, 16B per lane; LDS dest = first-lane base + lane*16 (linear)
static __device__ __forceinline__ void gload_lds16(const void* g, void* l) {
    __builtin_amdgcn_global_load_lds(
        (const __attribute__((address_space(1))) unsigned int*)g,
        (__attribute__((address_space(3))) unsigned int*)l, 16, 0, 0);
}

// ---------------- prep: x fp32->bf16 copy (blocks 0..4095) + RoPE table (4096..4351) ----
__global__ __launch_bounds__(256)
void prep_x_rope(const float* __restrict__ src, unsigned short* __restrict__ dst,
                 const int* __restrict__ pos, float2* __restrict__ RC)
{
    const int blk = blockIdx.x;
    if (blk < 4096) {
        const int i = blk * 256 + threadIdx.x;     // 1048576 u32x4 chunks
        const float4 f0 = ((const float4*)src)[i * 2];
        const float4 f1 = ((const float4*)src)[i * 2 + 1];
        u32x4 wv;
        wv.x = pack2bf(f0.x, f0.y); wv.y = pack2bf(f0.z, f0.w);
        wv.z = pack2bf(f1.x, f1.y); wv.w = pack2bf(f1.z, f1.w);
        ((u32x4*)dst)[i] = wv;
    } else {
        const int i = (blk - 4096) * 256 + threadIdx.x;   // 65536 entries
        const int t = i >> 5, dp = i & 31;
        const float ifr = __powf(10000.0f, -(float)(2 * dp) * (1.0f / 64.0f));
        float s, c;
        __sincosf((float)pos[t] * ifr, &s, &c);
        RC[i] = make_float2(c, s);
    }
}

// ---------------- prep: fp32 [K][N] -> bf16 transposed [N][K] ----------------
__global__ __launch_bounds__(256)
void convert_T(const float* __restrict__ src, unsigned short* __restrict__ dst, int K, int N)
{
    __shared__ float tile[32][33];
    const int n0 = blockIdx.x * 32, k0 = blockIdx.y * 32;
    const int tid = threadIdx.x;
    #pragma unroll
    for (int p = 0; p < 4; ++p) {
        const int idx = p * 256 + tid;
        const int r = idx >> 5, c = idx & 31;
        tile[r][c] = src[(size_t)(k0 + r) * N + n0 + c];
    }
    __syncthreads();
    #pragma unroll
    for (int p = 0; p < 4; ++p) {
        const int idx = p * 256 + tid;
        const int r = idx >> 5, c = idx & 31;
        dst[(size_t)(n0 + r) * K + k0 + c] = (unsigned short)f2bf(tile[c][r]);
    }
}

// ============ Kernel 1: QKV GEMM (bf16 MFMA) + RoPE, 3-buffer counted-vmcnt pipeline ====
__global__ __launch_bounds__(256, 3)
void qkv_rope_kernel(const unsigned short* __restrict__ xb,     // [8192][1024] bf16
                     const unsigned short* __restrict__ WT,     // [3072][1024] bf16 (Wqkv^T)
                     const float2* __restrict__ RC,             // [2048][32] {cos,sin}
                     unsigned short* __restrict__ Qb,
                     unsigned short* __restrict__ Kb,
                     unsigned short* __restrict__ Vtb)
{
    __shared__ u32x4 Asv[3][512];   // [buf][kb 4][row 128]; 24 KB
    __shared__ u32x4 Bsv[3][512];   // 24 KB; total 48 KB -> 3 blocks/CU
    const int tid  = threadIdx.x;
    const int lin  = blockIdx.x;          // 1536 = 8 XCDs * 3 cols * 64 rows
    const int xcd  = lin & 7;
    const int idx  = lin >> 3;            // 0..191
    const int col0 = (xcd * 3 + (idx % 3)) * 128;
    const int row0 = (idx / 3) * 128;
    const int l = tid & 63, w = tid >> 6;
    const int wr = w >> 1, wc = w & 1;
    const int lr = l & 15, hi4 = l >> 4;

    const int srow = tid & 127;
    const int kel  = (tid >> 7) * 8;
    const size_t a0 = (size_t)(row0 + srow) * DM + kel;
    const size_t b0 = (size_t)(col0 + srow) * DM + kel;

    f32x4 acc[4][4];
    #pragma unroll
    for (int m = 0; m < 4; ++m)
        #pragma unroll
        for (int n = 0; n < 4; ++n)
            acc[m][n] = (f32x4){0.f, 0.f, 0.f, 0.f};

    // prologue: slab 0 -> buf0, slab 1 -> buf1 (8 loads outstanding)
    gload_lds16(&xb[a0],      &Asv[0][tid]);
    gload_lds16(&xb[a0 + 16], &Asv[0][256 + tid]);
    gload_lds16(&WT[b0],      &Bsv[0][tid]);
    gload_lds16(&WT[b0 + 16], &Bsv[0][256 + tid]);
    gload_lds16(&xb[a0 + 32], &Asv[1][tid]);
    gload_lds16(&xb[a0 + 48], &Asv[1][256 + tid]);
    gload_lds16(&WT[b0 + 32], &Bsv[1][tid]);
    gload_lds16(&WT[b0 + 48], &Bsv[1][256 + tid]);
    asm volatile("s_waitcnt vmcnt(4)" ::: "memory");   // slab 0 landed
    __builtin_amdgcn_s_barrier();

    #pragma unroll 1
    for (int it = 0; it < 32; ++it) {
        const int cur = it % 3;
        const bool more = (it + 2 < 32);
        if (more) {                        // prefetch slab it+2 into buf (it+2)%3
            const int nb = (it + 2) % 3;
            const int kn = (it + 2) * 32;
            gload_lds16(&xb[a0 + kn],      &Asv[nb][tid]);
            gload_lds16(&xb[a0 + kn + 16], &Asv[nb][256 + tid]);
            gload_lds16(&WT[b0 + kn],      &Bsv[nb][tid]);
            gload_lds16(&WT[b0 + kn + 16], &Bsv[nb][256 + tid]);
        }
        u32x4 a[4], b[4];
        #pragma unroll
        for (int m = 0; m < 4; ++m) a[m] = Asv[cur][hi4 * 128 + wr * 64 + m * 16 + lr];
        #pragma unroll
        for (int n = 0; n < 4; ++n) b[n] = Bsv[cur][hi4 * 128 + wc * 64 + n * 16 + lr];
        #pragma unroll
        for (int m = 0; m < 4; ++m)
            #pragma unroll
            for (int n = 0; n < 4; ++n)
                acc[m][n] = __builtin_amdgcn_mfma_f32_16x16x32_bf16(
                    __builtin_bit_cast(bf16x8, a[m]),
                    __builtin_bit_cast(bf16x8, b[n]),
                    acc[m][n], 0, 0, 0);
        if (more) asm volatile("s_waitcnt vmcnt(4)" ::: "memory");
        else      asm volatile("s_waitcnt vmcnt(0)" ::: "memory");
        __builtin_amdgcn_s_barrier();
    }

    const int which = col0 >> 10;                      // 0=q 1=k 2=v (tile never crosses)
    const int h     = ((col0 & 1023) >> 6) + wc;
    const int bb    = row0 >> 11;
    const int t0w   = (row0 & 2047) + wr * 64;

    if (which == 2) {
        // V: lane holds t-run of 4 for fixed d -> free transpose, write Vt[d][t]
        #pragma unroll
        for (int n = 0; n < 4; ++n) {
            const int d = n * 16 + lr;
            #pragma unroll
            for (int m = 0; m < 4; ++m) {
                uint2 val;
                val.x = pack2bf(acc[m][n][0], acc[m][n][1]);
                val.y = pack2bf(acc[m][n][2], acc[m][n][3]);
                *(uint2*)&Vtb[((size_t)(bb * H_ + h) * DK + d) * T_ + t0w + m * 16 + hi4 * 4] = val;
            }
        }
    } else {
        unsigned short* dst = (which == 0) ? Qb : Kb;
        const float postscale = (which == 0) ? 0.125f : 1.0f;   // fold 1/sqrt(dk) into Q
        #pragma unroll
        for (int n = 0; n < 4; ++n) {
            const int d  = n * 16 + lr;
            const int dp = d >> 1;
            #pragma unroll
            for (int m = 0; m < 4; ++m)
                #pragma unroll
                for (int r = 0; r < 4; ++r) {
                    const int t = t0w + m * 16 + hi4 * 4 + r;
                    const float v = acc[m][n][r];
                    const float partner = __shfl_xor(v, 1, 64);   // pair (d^1)
                    const float2 cs = RC[t * 32 + dp];            // {cos, sin}
                    const float rv = ((d & 1) ? (partner * cs.y + v * cs.x)
                                              : (v * cs.x - partner * cs.y)) * postscale;
                    dst[((size_t)(bb * H_ + h) * T_ + t) * DK + d] = (unsigned short)f2bf(rv);
                }
        }
    }
}

// ============ Kernel 2: causal flash attention, Q-tile 256 (8 waves), T14 staging ============
// XCD swizzle: lin%8 = headgroup%8 -> all 8 q-blocks of one head on one XCD.
__global__ __launch_bounds__(512)
void flash_attn_kernel(const unsigned short* __restrict__ Qg,
                       const unsigned short* __restrict__ Kg,
                       const unsigned short* __restrict__ Vtg,
                       unsigned short* __restrict__ Og)
{
    __shared__ u32x4 K4[512];              // [kv 64][chunk 8], chunk ^= kv&7
    __shared__ u32x4 Vt4[512];             // [d 64][chunk 8],  chunk ^= d&7
    __shared__ unsigned int Pex[8][16 * 36];  // per-wave [q 16][word], stride 36

    const int tid = threadIdx.x;
    const int l = tid & 63, w = tid >> 6;  // w in 0..7
    const int lr = l & 15, hi4 = l >> 4;
    const int lin = blockIdx.x;            // 512 blocks
    const int qt  = 7 - (lin >> 6);        // longest q-tiles first
    const int g   = lin & 63;              // headgroup: same g -> same XCD (g%8)
    const int h   = g & 15, b = g >> 4;
    const int q0 = qt * 256;
    const size_t hb = (size_t)(b * H_ + h) * T_ * DK;
    unsigned int* pw = &Pex[w][0];

    // staging coords: thread owns exactly 1 chunk of K and 1 of Vt
    const int srow = tid >> 3, scc = tid & 7;
    const int sdst = srow * 8 + (scc ^ (srow & 7));

    // Q fragments (B-operand: col=lr -> q-row, k=d=ks*32+hi4*8+j)
    u32x4 qf[2][2];
    #pragma unroll
    for (int m = 0; m < 2; ++m)
        #pragma unroll
        for (int ks = 0; ks < 2; ++ks)
            qf[m][ks] = *(const u32x4*)&Qg[hb + (size_t)(q0 + w * 32 + m * 16 + lr) * DK
                                           + ks * 32 + hi4 * 8];

    f32x4 acc_ot[2][4];                    // [m][df]: O^T frag, col=q(lr), row=d
    float m_i[2], l_i[2];
    #pragma unroll
    for (int m = 0; m < 2; ++m) {
        m_i[m] = -INFINITY; l_i[m] = 0.f;
        #pragma unroll
        for (int df = 0; df < 4; ++df) acc_ot[m][df] = (f32x4){0.f, 0.f, 0.f, 0.f};
    }

    const int qwave = q0 + w * 32;
    const int nkt = (q0 >> 6) + 4;         // K/V tiles covering q0..q0+255

    // prologue: issue loads for tile 0
    u32x4 kr = *(const u32x4*)&Kg [hb + (size_t)srow * DK + scc * 8];
    u32x4 vr = *(const u32x4*)&Vtg[hb + (size_t)srow * T_ + scc * 8];

    for (int kt = 0; kt < nkt; ++kt) {
        const int kv0 = kt * 64;
        __syncthreads();                   // prev iter's LDS reads done
        K4[sdst] = kr; Vt4[sdst] = vr;
        __syncthreads();                   // staged data visible
        if (kt + 1 < nkt) {                // issue NEXT tile's loads; latency hides under compute
            const int kvn = kv0 + 64;
            kr = *(const u32x4*)&Kg [hb + (size_t)(kvn + srow) * DK + scc * 8];
            vr = *(const u32x4*)&Vtg[hb + (size_t)srow * T_ + kvn + scc * 8];
        }
        if (kv0 > qwave + 31) continue;    // wave-uniform: fully masked

        // ---- S^T = mfma(K, Q): D col=q(lr), row=kv(nf*16+hi4*4+r) ----
        f32x4 st[2][4];
        #pragma unroll
        for (int m = 0; m < 2; ++m)
            #pragma unroll
            for (int nf = 0; nf < 4; ++nf)
                st[m][nf] = (f32x4){0.f, 0.f, 0.f, 0.f};
        #pragma unroll
        for (int ks = 0; ks < 2; ++ks) {
            u32x4 kb4[4];
            #pragma unroll
            for (int nf = 0; nf < 4; ++nf) {
                const int row = nf * 16 + lr;
                kb4[nf] = K4[row * 8 + ((ks * 4 + hi4) ^ (row & 7))];
            }
            #pragma unroll
            for (int m = 0; m < 2; ++m)
                #pragma unroll
                for (int nf = 0; nf < 4; ++nf)
                    st[m][nf] = __builtin_amdgcn_mfma_f32_16x16x32_bf16(
                        __builtin_bit_cast(bf16x8, kb4[nf]),
                        __builtin_bit_cast(bf16x8, qf[m][ks]), st[m][nf], 0, 0, 0);
        }

        const bool needmask = (kv0 + 63 > qwave);
        u32x4 pfrag[2][2];
        #pragma unroll
        for (int m = 0; m < 2; ++m) {
            const int qg = qwave + m * 16 + lr;
            float sv[4][4];
            #pragma unroll
            for (int nf = 0; nf < 4; ++nf)
                #pragma unroll
                for (int r = 0; r < 4; ++r) {
                    float xv = st[m][nf][r];
                    if (needmask && (kv0 + nf * 16 + hi4 * 4 + r) > qg) xv = -INFINITY;
                    sv[nf][r] = xv;
                }
            // row max: 15 local + 2 shuffles (over hi4 groups)
            float mx = sv[0][0];
            #pragma unroll
            for (int nf = 0; nf < 4; ++nf)
                #pragma unroll
                for (int r = 0; r < 4; ++r) mx = fmaxf(mx, sv[nf][r]);
            mx = fmaxf(mx, __shfl_xor(mx, 16, 64));
            mx = fmaxf(mx, __shfl_xor(mx, 32, 64));
            const float mnew = fmaxf(m_i[m], mx);
            const float alpha = __expf(m_i[m] - mnew);
            m_i[m] = mnew;
            float p[4][4], rs = 0.f;
            #pragma unroll
            for (int nf = 0; nf < 4; ++nf)
                #pragma unroll
                for (int r = 0; r < 4; ++r) {
                    p[nf][r] = __expf(sv[nf][r] - mnew);
                    rs += p[nf][r];
                }
            rs += __shfl_xor(rs, 16, 64);
            rs += __shfl_xor(rs, 32, 64);
            l_i[m] = l_i[m] * alpha + rs;
            #pragma unroll
            for (int df = 0; df < 4; ++df) acc_ot[m][df] *= alpha;
            // pack P row -> per-wave LDS exchange [q=lr][word=kv/2], stride 36
            #pragma unroll
            for (int nf = 0; nf < 4; ++nf) {
                uint2 pr;
                pr.x = pack2bf(p[nf][0], p[nf][1]);
                pr.y = pack2bf(p[nf][2], p[nf][3]);
                *(uint2*)&pw[lr * 36 + nf * 8 + hi4 * 2] = pr;
            }
            // read back as B-frag: col=q(lr), k = kv = ks*32 + hi4*8 + j
            #pragma unroll
            for (int ks = 0; ks < 2; ++ks)
                pfrag[m][ks] = *(const u32x4*)&pw[lr * 36 + ks * 16 + hi4 * 4];
        }

        // ---- O^T += mfma(Vt, P): col=q(lr), row=d ----
        #pragma unroll
        for (int ks = 0; ks < 2; ++ks) {
            u32x4 vb[4];
            #pragma unroll
            for (int df = 0; df < 4; ++df) {
                const int d = df * 16 + lr;
                vb[df] = Vt4[d * 8 + ((ks * 4 + hi4) ^ (d & 7))];
            }
            #pragma unroll
            for (int m = 0; m < 2; ++m)
                #pragma unroll
                for (int df = 0; df < 4; ++df)
                    acc_ot[m][df] = __builtin_amdgcn_mfma_f32_16x16x32_bf16(
                        __builtin_bit_cast(bf16x8, vb[df]),
                        __builtin_bit_cast(bf16x8, pfrag[m][ks]), acc_ot[m][df], 0, 0, 0);
        }
    }

    // ---- epilogue: O^T -> O via per-wave LDS, then coalesced bf16 stores ----
    #pragma unroll
    for (int m = 0; m < 2; ++m) {
        const float inv = 1.0f / l_i[m];
        #pragma unroll
        for (int df = 0; df < 4; ++df) {
            uint2 pr;
            pr.x = pack2bf(acc_ot[m][df][0] * inv, acc_ot[m][df][1] * inv);
            pr.y = pack2bf(acc_ot[m][df][2] * inv, acc_ot[m][df][3] * inv);
            *(uint2*)&pw[lr * 36 + df * 8 + hi4 * 2] = pr;
        }
        #pragma unroll
        for (int ks2 = 0; ks2 < 2; ++ks2) {
            const u32x4 ov = *(const u32x4*)&pw[lr * 36 + ks2 * 16 + hi4 * 4];
            *(u32x4*)&Og[hb + (size_t)(qwave + m * 16 + lr) * DK + ks2 * 32 + hi4 * 8] = ov;
        }
    }
}

// ============ Kernel 3: output projection (bf16 MFMA), XCD-ownership swizzle ============
__global__ __launch_bounds__(256)
void out_proj_kernel(const unsigned short* __restrict__ Ob,   // [b][h][t][d] bf16
                     const unsigned short* __restrict__ WoT,  // [1024][1024] bf16 (Wo^T)
                     float* __restrict__ out)
{
    __shared__ u32x4 Asv[512];
    __shared__ u32x4 Bsv[512];
    const int tid  = threadIdx.x;
    const int lin  = blockIdx.x;          // 512 = 8 XCDs * 64 rows
    const int col0 = (lin & 7) * 128;
    const int row0 = (lin >> 3) * 128;
    const int l = tid & 63, w = tid >> 6;
    const int wr = w >> 1, wc = w & 1;
    const int lr = l & 15, hi4 = l >> 4;
    const int bb = row0 >> 11, trow0 = row0 & 2047;

    f32x4 acc[4][4];
    #pragma unroll
    for (int m = 0; m < 4; ++m)
        #pragma unroll
        for (int n = 0; n < 4; ++n)
            acc[m][n] = (f32x4){0.f, 0.f, 0.f, 0.f};

    for (int k0 = 0; k0 < DM; k0 += 32) {
        __syncthreads();
        #pragma unroll
        for (int pass = 0; pass < 2; ++pass) {
            const int i = pass * 256 + tid;
            const int row = i & 127, kb = i >> 7;
            const int k = k0 + kb * 8;
            const int hh = k >> 6, dd = k & 63;
            gload_lds16(&Ob[((size_t)(bb * H_ + hh) * T_ + trow0 + row) * DK + dd], &Asv[i]);
            gload_lds16(&WoT[(size_t)(col0 + row) * DM + k0 + kb * 8], &Bsv[i]);
        }
        __syncthreads();
        u32x4 a[4], b[4];
        #pragma unroll
        for (int m = 0; m < 4; ++m) a[m] = Asv[hi4 * 128 + wr * 64 + m * 16 + lr];
        #pragma unroll
        for (int n = 0; n < 4; ++n) b[n] = Bsv[hi4 * 128 + wc * 64 + n * 16 + lr];
        #pragma unroll
        for (int m = 0; m < 4; ++m)
            #pragma unroll
            for (int n = 0; n < 4; ++n)
                acc[m][n] = __builtin_amdgcn_mfma_f32_16x16x32_bf16(
                    __builtin_bit_cast(bf16x8, a[m]),
                    __builtin_bit_cast(bf16x8, b[n]),
                    acc[m][n], 0, 0, 0);
    }

    #pragma unroll
    for (int n = 0; n < 4; ++n) {
        const int gc = col0 + wc * 64 + n * 16 + lr;
        #pragma unroll
        for (int m = 0; m < 4; ++m)
            #pragma unroll
            for (int r = 0; r < 4; ++r)
                out[(size_t)(row0 + wr * 64 + m * 16 + hi4 * 4 + r) * DM + gc] = acc[m][n][r];
    }
}

extern "C" void kernel_launch(void* const* d_in, const int* in_sizes, int n_in,
                              void* d_out, int out_size, void* d_ws, size_t ws_size,
                              hipStream_t stream)
{
    const float* x    = (const float*)d_in[0];
    const float* Wqkv = (const float*)d_in[1];
    const float* Wo   = (const float*)d_in[2];
    const int*   pos  = (const int*)d_in[3];
    float* out = (float*)d_out;

    unsigned short* ws    = (unsigned short*)d_ws;
    unsigned short* xb    = ws;                      // 8388608
    unsigned short* WqkvT = xb    + 8388608;         // 3145728
    unsigned short* WoT   = WqkvT + 3145728;         // 1048576
    unsigned short* Qb    = WoT   + 1048576;         // 8388608
    unsigned short* Kb    = Qb    + 8388608;         // 8388608
    unsigned short* Vtb   = Kb    + 8388608;         // 8388608  ([b][h][d][t])
    unsigned short* Ob    = Vtb   + 8388608;         // 8388608
    float2*         RC    = (float2*)(Ob + 8388608); // 65536 float2 = 512 KB

    prep_x_rope<<<dim3(4352), 256, 0, stream>>>(x, xb, pos, RC);
    convert_T<<<dim3(96, 32), 256, 0, stream>>>(Wqkv, WqkvT, 1024, 3072);
    convert_T<<<dim3(32, 32), 256, 0, stream>>>(Wo, WoT, 1024, 1024);
    qkv_rope_kernel<<<dim3(1536), 256, 0, stream>>>(xb, WqkvT, RC, Qb, Kb, Vtb);
    flash_attn_kernel<<<dim3(512), 512, 0, stream>>>(Qb, Kb, Vtb, Ob);
    out_proj_kernel<<<dim3(512), 256, 0, stream>>>(Ob, WoT, out);
}